// Round 1
// baseline (515.477 us; speedup 1.0000x reference)
//
#include <hip/hip_runtime.h>
#include <stdint.h>

#define DEVI __device__ __forceinline__

typedef __attribute__((ext_vector_type(8))) uint16_t u16x8;
typedef __attribute__((ext_vector_type(4))) uint16_t u16x4v;
typedef __attribute__((ext_vector_type(8))) __bf16 bf16x8;
typedef __attribute__((ext_vector_type(4))) float f32x4;

DEVI uint16_t f2bf(float x) {
  union { float f; uint32_t u; } v; v.f = x;
  return (uint16_t)((v.u + 0x7fffu + ((v.u >> 16) & 1u)) >> 16);
}

DEVI f32x4 mfma16(u16x8 a, u16x8 b, f32x4 c) {
  return __builtin_amdgcn_mfma_f32_16x16x32_bf16(
      __builtin_bit_cast(bf16x8, a), __builtin_bit_cast(bf16x8, b), c, 0, 0, 0);
}

DEVI void async16(void* lds, const void* g) {
  __builtin_amdgcn_global_load_lds(
      (const __attribute__((address_space(1))) uint32_t*)g,
      (__attribute__((address_space(3))) uint32_t*)lds, 16, 0, 0);
}

// ---------------- elementwise f32 -> bf16 ----------------
__global__ void cvt_f32_bf16(const float* __restrict__ in, uint16_t* __restrict__ out, int n4) {
  int i = blockIdx.x * blockDim.x + threadIdx.x;
  const int st = gridDim.x * blockDim.x;
  for (; i < n4; i += st) {
    float4 v = ((const float4*)in)[i];
    u16x4v o;
    o[0] = f2bf(v.x); o[1] = f2bf(v.y); o[2] = f2bf(v.z); o[3] = f2bf(v.w);
    ((u16x4v*)out)[i] = o;
  }
}

// ------------- transpose + convert: f32 [K][N] -> bf16 [N][K] -------------
__global__ void transp_cvt(const float* __restrict__ in, uint16_t* __restrict__ out,
                           int K, int N) {
  __shared__ float Ws[64][65];
  const int n0 = blockIdx.x * 64, k0 = blockIdx.y * 64;
  const int t = threadIdx.x;
  const int r = t >> 4, c = (t & 15) << 2;
#pragma unroll
  for (int it = 0; it < 4; ++it) {
    float4 v = *(const float4*)&in[(size_t)(k0 + it * 16 + r) * N + n0 + c];
    Ws[it * 16 + r][c] = v.x; Ws[it * 16 + r][c + 1] = v.y;
    Ws[it * 16 + r][c + 2] = v.z; Ws[it * 16 + r][c + 3] = v.w;
  }
  __syncthreads();
#pragma unroll
  for (int it = 0; it < 4; ++it) {
    const int rr = it * 16 + r;   // n index in tile
    const int cc = c;             // k index in tile
    ushort4 o;
    o.x = f2bf(Ws[cc][rr]);     o.y = f2bf(Ws[cc + 1][rr]);
    o.z = f2bf(Ws[cc + 2][rr]); o.w = f2bf(Ws[cc + 3][rr]);
    *(ushort4*)&out[(size_t)(n0 + rr) * K + k0 + cc] = o;
  }
}

// ------------- transpose bf16: [BH][T][128] -> [BH][128][T] -------------
__global__ void transp_v(const uint16_t* __restrict__ in, uint16_t* __restrict__ out, int T) {
  __shared__ uint16_t Vs[64][72];
  const int t0 = blockIdx.x * 64, d0 = blockIdx.y * 64, bh = blockIdx.z;
  const uint16_t* ip = in + (size_t)bh * T * 128;
  uint16_t* op = out + (size_t)bh * 128 * T;
  const int t = threadIdx.x;
  const int r = t >> 3, c = (t & 7) << 3;
#pragma unroll
  for (int it = 0; it < 2; ++it) {
    u16x8 v = *(const u16x8*)&ip[(size_t)(t0 + it * 32 + r) * 128 + d0 + c];
#pragma unroll
    for (int j = 0; j < 8; ++j) Vs[it * 32 + r][c + j] = v[j];
  }
  __syncthreads();
#pragma unroll
  for (int it = 0; it < 2; ++it) {
    const int rr = it * 32 + r;  // d index in tile
    const int cc = c;            // t index in tile
    u16x8 o;
#pragma unroll
    for (int j = 0; j < 8; ++j) o[j] = Vs[cc + j][rr];
    *(u16x8*)&op[(size_t)(d0 + rr) * T + t0 + cc] = o;
  }
}

// ------------- GEMM: C[M][N] = A[M][K] * Bt[N][K]^T + bias -------------
// EPI==0: scatter bf16 into q/k/v layouts (qkv fused epilogue), T=2048 hardcoded.
// EPI==1: f32 out[M][N].
template <int EPI>
__global__ __launch_bounds__(256, 2)
void gemm_bt(const uint16_t* __restrict__ A, const uint16_t* __restrict__ Bt,
             const float* __restrict__ bias, float* __restrict__ outF,
             uint16_t* __restrict__ q, uint16_t* __restrict__ kk, uint16_t* __restrict__ v,
             int M, int N, int K) {
  constexpr int BK = 32;
  __shared__ uint16_t As[128 * BK];
  __shared__ uint16_t Bs[128 * BK];
  const int nbn = N >> 7;
  const int brow = (int)(blockIdx.x / nbn) << 7;
  const int bcol = (int)(blockIdx.x % nbn) << 7;
  const int t = threadIdx.x;
  const int w = t >> 6, lane = t & 63;
  const int wr = ((w >> 1) << 6), wc = ((w & 1) << 6);
  const int lr = lane & 15, lk = (lane >> 4) << 3;
  const int sr = t >> 2;           // staging row 0..63
  const int sc = (t & 3) << 3;     // staging element offset in row

  f32x4 acc[4][4];
#pragma unroll
  for (int i = 0; i < 4; ++i)
#pragma unroll
    for (int j = 0; j < 4; ++j) acc[i][j] = f32x4{0.f, 0.f, 0.f, 0.f};

  const uint16_t* Ap = A + (size_t)(brow + sr) * K + sc;
  const uint16_t* Bp = Bt + (size_t)(bcol + sr) * K + sc;
  const size_t rowskip = (size_t)64 * K;

  for (int k0 = 0; k0 < K; k0 += BK) {
    async16(&As[sr * BK + sc], Ap + k0);
    async16(&As[(64 + sr) * BK + sc], Ap + rowskip + k0);
    async16(&Bs[sr * BK + sc], Bp + k0);
    async16(&Bs[(64 + sr) * BK + sc], Bp + rowskip + k0);
    __syncthreads();
    u16x8 af[4], bf[4];
#pragma unroll
    for (int i = 0; i < 4; ++i) af[i] = *(const u16x8*)&As[(wr + i * 16 + lr) * BK + lk];
#pragma unroll
    for (int j = 0; j < 4; ++j) bf[j] = *(const u16x8*)&Bs[(wc + j * 16 + lr) * BK + lk];
#pragma unroll
    for (int i = 0; i < 4; ++i)
#pragma unroll
      for (int j = 0; j < 4; ++j) acc[i][j] = mfma16(af[i], bf[j], acc[i][j]);
    __syncthreads();
  }

#pragma unroll
  for (int i = 0; i < 4; ++i) {
#pragma unroll
    for (int j = 0; j < 4; ++j) {
      const int col = bcol + wc + j * 16 + lr;
      const float bb = bias[col];
#pragma unroll
      for (int r = 0; r < 4; ++r) {
        const int row = brow + wr + i * 16 + ((lane >> 4) << 2) + r;
        const float val = acc[i][j][r] + bb;
        if (EPI == 1) {
          outF[(size_t)row * N + col] = val;
        } else {
          const uint16_t bv = f2bf(val);
          const int b_ = row >> 11, tt = row & 2047;
          const int d = col & 127;
          if (col < 2048) {
            const int hh = col >> 7;
            q[((size_t)((b_ * 16 + hh) * 2048 + tt) << 7) + d] = bv;
          } else if (col < 2560) {
            const int hh = (col - 2048) >> 7;
            kk[((size_t)((b_ * 4 + hh) * 2048 + tt) << 7) + d] = bv;
          } else {
            const int hh = (col - 2560) >> 7;
            v[((size_t)((b_ * 4 + hh) * 2048 + tt) << 7) + d] = bv;
          }
        }
      }
    }
  }
}

// ------------- flash attention (causal, GQA 4:1) -------------
// grid: (T/128, 16, B). 4 waves, each owns 32 q-rows. KV tile = 64.
__global__ __launch_bounds__(256, 2)
void attn_fwd(const uint16_t* __restrict__ Q,   // [B*16][T][128]
              const uint16_t* __restrict__ Kg,  // [B*4][T][128]
              const uint16_t* __restrict__ Vt,  // [B*4][128][T]
              uint16_t* __restrict__ Y,         // [B*T][2048], col offset h*128
              int T) {
  constexpr int KVB = 64;
  __shared__ uint16_t Ks[64][136];   // K tile, +8 pad
  __shared__ uint16_t Vs[128][72];   // V^T tile, +8 pad
  __shared__ uint16_t Ps[4][32][72]; // per-wave P, +8 pad
  const int qb = blockIdx.x, h = blockIdx.y, b = blockIdx.z;
  const int hkv = h >> 2;
  const int t = threadIdx.x, w = t >> 6, lane = t & 63;
  const int lr = lane & 15, lk = (lane >> 4) << 3;
  const int rq = (lane >> 4) << 2;

  const uint16_t* Qp = Q + ((size_t)(b * 16 + h) * T + qb * 128) * 128;
  const uint16_t* Kp = Kg + (size_t)(b * 4 + hkv) * T * 128;
  const uint16_t* Vp = Vt + (size_t)(b * 4 + hkv) * 128 * T;

  u16x8 qf[2][4];
#pragma unroll
  for (int mf = 0; mf < 2; ++mf)
#pragma unroll
    for (int kf = 0; kf < 4; ++kf)
      qf[mf][kf] = *(const u16x8*)&Qp[(size_t)(w * 32 + mf * 16 + lr) * 128 + kf * 32 + lk];

  f32x4 o[2][8];
  float mrow[2][4], lrow[2][4];
#pragma unroll
  for (int mf = 0; mf < 2; ++mf) {
#pragma unroll
    for (int nf = 0; nf < 8; ++nf) o[mf][nf] = f32x4{0.f, 0.f, 0.f, 0.f};
#pragma unroll
    for (int i = 0; i < 4; ++i) { mrow[mf][i] = -3e38f; lrow[mf][i] = 0.f; }
  }

  const int sKr = t >> 4, sKc = (t & 15) << 3;
  const int sVr = t >> 3, sVc = (t & 7) << 3;
  const int ntiles = 2 * qb + 2;

  for (int tile = 0; tile < ntiles; ++tile) {
    const int kv0 = tile * KVB;
#pragma unroll
    for (int it = 0; it < 4; ++it)
      *(u16x8*)&Ks[it * 16 + sKr][sKc] =
          *(const u16x8*)&Kp[(size_t)(kv0 + it * 16 + sKr) * 128 + sKc];
#pragma unroll
    for (int it = 0; it < 4; ++it)
      *(u16x8*)&Vs[it * 32 + sVr][sVc] =
          *(const u16x8*)&Vp[(size_t)(it * 32 + sVr) * T + kv0 + sVc];
    __syncthreads();

    // QK^T
    f32x4 s[2][4];
#pragma unroll
    for (int mf = 0; mf < 2; ++mf)
#pragma unroll
      for (int nf = 0; nf < 4; ++nf) s[mf][nf] = f32x4{0.f, 0.f, 0.f, 0.f};
#pragma unroll
    for (int kf = 0; kf < 4; ++kf) {
#pragma unroll
      for (int nf = 0; nf < 4; ++nf) {
        u16x8 bfr = *(const u16x8*)&Ks[nf * 16 + lr][kf * 32 + lk];
        s[0][nf] = mfma16(qf[0][kf], bfr, s[0][nf]);
        s[1][nf] = mfma16(qf[1][kf], bfr, s[1][nf]);
      }
    }

    // online softmax
    const int row0 = qb * 128 + w * 32;
#pragma unroll
    for (int mf = 0; mf < 2; ++mf) {
#pragma unroll
      for (int i = 0; i < 4; ++i) {
        const int grow = row0 + mf * 16 + rq + i;
        float mx = -3e38f;
#pragma unroll
        for (int nf = 0; nf < 4; ++nf) {
          const int gcol = kv0 + nf * 16 + lr;
          float sv = s[mf][nf][i] * 0.08838834764831845f;
          sv = (gcol > grow) ? -3e38f : sv;
          s[mf][nf][i] = sv;
          mx = fmaxf(mx, sv);
        }
        mx = fmaxf(mx, __shfl_xor(mx, 1));
        mx = fmaxf(mx, __shfl_xor(mx, 2));
        mx = fmaxf(mx, __shfl_xor(mx, 4));
        mx = fmaxf(mx, __shfl_xor(mx, 8));
        const float mold = mrow[mf][i];
        const float mnew = fmaxf(mold, mx);
        const float scale = __expf(mold - mnew);
        mrow[mf][i] = mnew;
        float psum = 0.f;
#pragma unroll
        for (int nf = 0; nf < 4; ++nf) {
          const float p = __expf(s[mf][nf][i] - mnew);
          psum += p;
          Ps[w][mf * 16 + rq + i][nf * 16 + lr] = f2bf(p);
        }
        psum += __shfl_xor(psum, 1);
        psum += __shfl_xor(psum, 2);
        psum += __shfl_xor(psum, 4);
        psum += __shfl_xor(psum, 8);
        lrow[mf][i] = lrow[mf][i] * scale + psum;
#pragma unroll
        for (int nf = 0; nf < 8; ++nf) o[mf][nf][i] *= scale;
      }
    }

    // PV
#pragma unroll
    for (int kf = 0; kf < 2; ++kf) {
      u16x8 pa0 = *(const u16x8*)&Ps[w][lr][kf * 32 + lk];
      u16x8 pa1 = *(const u16x8*)&Ps[w][16 + lr][kf * 32 + lk];
#pragma unroll
      for (int nf = 0; nf < 8; ++nf) {
        u16x8 vb = *(const u16x8*)&Vs[nf * 16 + lr][kf * 32 + lk];
        o[0][nf] = mfma16(pa0, vb, o[0][nf]);
        o[1][nf] = mfma16(pa1, vb, o[1][nf]);
      }
    }
    __syncthreads();
  }

  uint16_t* Yp = Y + ((size_t)(b * T + qb * 128 + w * 32)) * 2048 + h * 128;
#pragma unroll
  for (int mf = 0; mf < 2; ++mf) {
#pragma unroll
    for (int i = 0; i < 4; ++i) {
      const float inv = 1.f / lrow[mf][i];
      const int rr = mf * 16 + rq + i;
#pragma unroll
      for (int nf = 0; nf < 8; ++nf)
        Yp[(size_t)rr * 2048 + nf * 16 + lr] = f2bf(o[mf][nf][i] * inv);
    }
  }
}

extern "C" void kernel_launch(void* const* d_in, const int* in_sizes, int n_in,
                              void* d_out, int out_size, void* d_ws, size_t ws_size,
                              hipStream_t stream) {
  const float* x      = (const float*)d_in[0];
  const float* W_attn = (const float*)d_in[1];
  const float* b_attn = (const float*)d_in[2];
  const float* W_proj = (const float*)d_in[3];
  const float* b_proj = (const float*)d_in[4];
  float* out = (float*)d_out;

  const int B = 4, T = 2048, C = 2048, H = 16, HKV = 4, HS = 128;
  const int M = B * T;               // 8192
  const int Nqkv = C + 2 * HKV * HS; // 3072

  uint8_t* ws = (uint8_t*)d_ws;
  size_t off = 0;
  auto alloc = [&](size_t bytes) {
    void* p = ws + off;
    off += (bytes + 255) & ~(size_t)255;
    return p;
  };
  uint16_t* xb  = (uint16_t*)alloc((size_t)M * C * 2);      // reused as yb after qkv
  uint16_t* WaT = (uint16_t*)alloc((size_t)Nqkv * C * 2);
  uint16_t* WpT = (uint16_t*)alloc((size_t)C * C * 2);
  uint16_t* qb  = (uint16_t*)alloc((size_t)B * H * T * HS * 2);
  uint16_t* kb  = (uint16_t*)alloc((size_t)B * HKV * T * HS * 2);
  uint16_t* vb  = (uint16_t*)alloc((size_t)B * HKV * T * HS * 2);
  uint16_t* vtb = (uint16_t*)alloc((size_t)B * HKV * HS * T * 2);
  uint16_t* yb  = xb;

  cvt_f32_bf16<<<2048, 256, 0, stream>>>(x, xb, M * C / 4);
  transp_cvt<<<dim3(Nqkv / 64, C / 64), 256, 0, stream>>>(W_attn, WaT, C, Nqkv);
  transp_cvt<<<dim3(C / 64, C / 64), 256, 0, stream>>>(W_proj, WpT, C, C);
  gemm_bt<0><<<dim3((M / 128) * (Nqkv / 128)), 256, 0, stream>>>(
      xb, WaT, b_attn, nullptr, qb, kb, vb, M, Nqkv, C);
  transp_v<<<dim3(T / 64, 2, B * HKV), 256, 0, stream>>>(vb, vtb, T);
  attn_fwd<<<dim3(T / 128, H, B), 256, 0, stream>>>(qb, kb, vtb, yb, T);
  gemm_bt<1><<<dim3((M / 128) * (C / 128)), 256, 0, stream>>>(
      yb, WpT, b_proj, out, nullptr, nullptr, nullptr, M, C, C);
}